// Round 1
// baseline (241.119 us; speedup 1.0000x reference)
//
#include <hip/hip_runtime.h>
#include <math.h>

#define NFEAT 256
#define NROWS 65536
#define PCOUNT 4194304

constexpr double D_LN2 = 0.6931471805599453;
constexpr double D_HALF_LOG2_2PIE = 0.5 * 2.8378770664093453 / D_LN2; // 0.5*log2(2*pi*e)
constexpr double D_LAMBDA_BITS = 13.287712379549449;                  // 2*log2(100)
#define F_EPS 5.9604645e-07f                                           // float32 eps * 5

__device__ inline double wave_reduce_add(double v) {
  for (int o = 32; o > 0; o >>= 1) v += __shfl_down(v, o, 64);
  return v;
}

// Pass 1: thread t = feature t; block c covers rows [c*R, (c+1)*R).
// Fused evaluation of all 6 lambda proposals; 18 float accumulators.
__global__ __launch_bounds__(256) void k_pass1(
    const float* __restrict__ x, const float* __restrict__ lam1,
    const float* __restrict__ lam2, const float* __restrict__ rp,
    float* __restrict__ P1, int rowsPerBlock)
{
  const int t = threadIdx.x;
  const int c = blockIdx.x;
  const float L1 = lam1[t], L2 = lam2[t];

  // per-proposal precomputed coefficients:
  // y  = s*(exp(a*u)-1) + tt*u   (a,s,tt selected by sign branch)
  // lj = cc*u
  float a_p[6], a_n[6], s_p[6], s_n[6], t_p[6], t_n[6], c_p[6], c_n[6];
#pragma unroll
  for (int j = 0; j < 6; ++j) {
    float l1 = (j == 0) ? L1 : L1 + 0.1f * rp[t * 10 + 2 * (j - 1)];
    float l2 = (j == 0) ? L2 : L2 + 0.1f * rp[t * 10 + 2 * (j - 1) + 1];
    bool z1 = fabsf(l1) < F_EPS;
    bool z2 = fabsf(l2 - 2.0f) < F_EPS;
    float tm = 2.0f - l2;
    a_p[j] = l1;
    a_n[j] = tm;
    s_p[j] = z1 ? 0.0f : 1.0f / l1;
    t_p[j] = z1 ? 1.0f : 0.0f;
    c_p[j] = z1 ? -1.0f : l1 - 1.0f;
    s_n[j] = z2 ? 0.0f : -1.0f / tm;
    t_n[j] = z2 ? -1.0f : 0.0f;
    c_n[j] = z2 ? -1.0f : 1.0f - l2;
  }

  float as[6], aq[6], al[6];
#pragma unroll
  for (int j = 0; j < 6; ++j) { as[j] = 0.f; aq[j] = 0.f; al[j] = 0.f; }

  const size_t rowBase = (size_t)c * rowsPerBlock;
  for (int i = 0; i < rowsPerBlock; ++i) {
    float v = x[(rowBase + i) * NFEAT + t];
    bool pos = v >= 0.0f;
    float u = log1pf(fabsf(v));
#pragma unroll
    for (int j = 0; j < 6; ++j) {
      float a  = pos ? a_p[j] : a_n[j];
      float s  = pos ? s_p[j] : s_n[j];
      float tt = pos ? t_p[j] : t_n[j];
      float cc = pos ? c_p[j] : c_n[j];
      float em1 = __expf(a * u) - 1.0f;
      float y = fmaf(s, em1, tt * u);
      as[j] += y;
      aq[j] = fmaf(y, y, aq[j]);
      al[j] = fmaf(cc, u, al[j]);
    }
  }
#pragma unroll
  for (int j = 0; j < 6; ++j) {
    P1[((size_t)c * 18 + j * 3 + 0) * NFEAT + t] = as[j];
    P1[((size_t)c * 18 + j * 3 + 1) * NFEAT + t] = aq[j];
    P1[((size_t)c * 18 + j * 3 + 2) * NFEAT + t] = al[j];
  }
}

// Reduce pass-1 partials per feature, compute 6 scores, tie-averaged best lambdas.
__global__ __launch_bounds__(64) void k_pick(
    const float* __restrict__ P1, const float* __restrict__ lam1,
    const float* __restrict__ lam2, const float* __restrict__ rp,
    float* __restrict__ bestL, int chunks)
{
  const int f = blockIdx.x;
  const int lane = threadIdx.x;
  double s[18];
#pragma unroll
  for (int k = 0; k < 18; ++k) s[k] = 0.0;
  for (int c = lane; c < chunks; c += 64) {
#pragma unroll
    for (int k = 0; k < 18; ++k)
      s[k] += (double)P1[((size_t)c * 18 + k) * NFEAT + f];
  }
#pragma unroll
  for (int k = 0; k < 18; ++k) s[k] = wave_reduce_add(s[k]);

  if (lane == 0) {
    const float L1 = lam1[f], L2 = lam2[f];
    const double n = (double)NROWS;
    double scores[6]; float al1[6], al2[6];
#pragma unroll
    for (int j = 0; j < 6; ++j) {
      al1[j] = (j == 0) ? L1 : L1 + 0.1f * rp[f * 10 + 2 * (j - 1)];
      al2[j] = (j == 0) ? L2 : L2 + 0.1f * rp[f * 10 + 2 * (j - 1) + 1];
      double mean = s[j * 3 + 0] / n;
      double var = s[j * 3 + 1] / n - mean * mean;
      var = var > 1e-12 ? var : 1e-12;
      scores[j] = n * (D_HALF_LOG2_2PIE + 0.5 * log2(var))
                + s[j * 3 + 2] / D_LN2 + D_LAMBDA_BITS;
    }
    double mn = scores[0];
#pragma unroll
    for (int j = 1; j < 6; ++j) mn = scores[j] < mn ? scores[j] : mn;
    double wsum = 0.0, b1 = 0.0, b2 = 0.0;
#pragma unroll
    for (int j = 0; j < 6; ++j) {
      double w = (scores[j] == mn) ? 1.0 : 0.0;
      wsum += w; b1 += w * (double)al1[j]; b2 += w * (double)al2[j];
    }
    if (wsum < 1e-8) wsum = 1e-8;
    bestL[2 * f]     = (float)(b1 / wsum);
    bestL[2 * f + 1] = (float)(b2 / wsum);
  }
}

// Pass 2: re-evaluate at best lambdas; 3 accumulators.
__global__ __launch_bounds__(256) void k_pass2(
    const float* __restrict__ x, const float* __restrict__ bestL,
    float* __restrict__ P2, int rowsPerBlock)
{
  const int t = threadIdx.x;
  const int c = blockIdx.x;
  const float l1 = bestL[2 * t], l2 = bestL[2 * t + 1];
  const bool z1 = fabsf(l1) < F_EPS;
  const bool z2 = fabsf(l2 - 2.0f) < F_EPS;
  const float tm = 2.0f - l2;
  const float a_p = l1,                 a_n = tm;
  const float s_p = z1 ? 0.f : 1.f/l1,  s_n = z2 ? 0.f : -1.f/tm;
  const float t_p = z1 ? 1.f : 0.f,     t_n = z2 ? -1.f : 0.f;
  const float c_p = z1 ? -1.f : l1-1.f, c_n = z2 ? -1.f : 1.f-l2;

  float as = 0.f, aq = 0.f, al = 0.f;
  const size_t rowBase = (size_t)c * rowsPerBlock;
  for (int i = 0; i < rowsPerBlock; ++i) {
    float v = x[(rowBase + i) * NFEAT + t];
    bool pos = v >= 0.0f;
    float u = log1pf(fabsf(v));
    float a  = pos ? a_p : a_n;
    float s  = pos ? s_p : s_n;
    float tt = pos ? t_p : t_n;
    float cc = pos ? c_p : c_n;
    float em1 = __expf(a * u) - 1.0f;
    float y = fmaf(s, em1, tt * u);
    as += y;
    aq = fmaf(y, y, aq);
    al = fmaf(cc, u, al);
  }
  P2[((size_t)c * 3 + 0) * NFEAT + t] = as;
  P2[((size_t)c * 3 + 1) * NFEAT + t] = aq;
  P2[((size_t)c * 3 + 2) * NFEAT + t] = al;
}

__global__ __launch_bounds__(64) void k_featbits(
    const float* __restrict__ P2, double* __restrict__ bitsF, int chunks)
{
  const int f = blockIdx.x, lane = threadIdx.x;
  double s0 = 0.0, s1 = 0.0, s2 = 0.0;
  for (int c = lane; c < chunks; c += 64) {
    s0 += (double)P2[((size_t)c * 3 + 0) * NFEAT + f];
    s1 += (double)P2[((size_t)c * 3 + 1) * NFEAT + f];
    s2 += (double)P2[((size_t)c * 3 + 2) * NFEAT + f];
  }
  s0 = wave_reduce_add(s0); s1 = wave_reduce_add(s1); s2 = wave_reduce_add(s2);
  if (lane == 0) {
    const double n = (double)NROWS;
    double mean = s0 / n;
    double var = s1 / n - mean * mean;
    var = var > 1e-12 ? var : 1e-12;
    bitsF[f] = n * (D_HALF_LOG2_2PIE + 0.5 * log2(var)) + s2 / D_LN2 + D_LAMBDA_BITS;
  }
}

__global__ __launch_bounds__(256) void k_param_reduce(
    const float* __restrict__ p, double* __restrict__ pSums)
{
  const float4* p4 = (const float4*)p;
  const size_t n4 = PCOUNT / 4;
  double s = 0.0, q = 0.0;
  for (size_t i = (size_t)blockIdx.x * 256 + threadIdx.x; i < n4;
       i += (size_t)gridDim.x * 256) {
    float4 v = p4[i];
    s += (double)v.x + (double)v.y + (double)v.z + (double)v.w;
    q += (double)v.x * v.x + (double)v.y * v.y
       + (double)v.z * v.z + (double)v.w * v.w;
  }
  s = wave_reduce_add(s); q = wave_reduce_add(q);
  __shared__ double ls[4], lq[4];
  int w = threadIdx.x >> 6;
  if ((threadIdx.x & 63) == 0) { ls[w] = s; lq[w] = q; }
  __syncthreads();
  if (threadIdx.x == 0) {
    atomicAdd(&pSums[0], ls[0] + ls[1] + ls[2] + ls[3]);
    atomicAdd(&pSums[1], lq[0] + lq[1] + lq[2] + lq[3]);
  }
}

__global__ __launch_bounds__(256) void k_final(
    const double* __restrict__ bitsF, const double* __restrict__ pSums,
    float* __restrict__ out)
{
  __shared__ double l[4];
  double s = bitsF[threadIdx.x];
  s = wave_reduce_add(s);
  int w = threadIdx.x >> 6;
  if ((threadIdx.x & 63) == 0) l[w] = s;
  __syncthreads();
  if (threadIdx.x == 0) {
    double data = l[0] + l[1] + l[2] + l[3];
    const double n = (double)PCOUNT;
    double mean = pSums[0] / n;
    double var = pSums[1] / n - mean * mean;
    var = var > 1e-12 ? var : 1e-12;
    double model = n * (D_HALF_LOG2_2PIE + 0.5 * log2(var)) + D_LAMBDA_BITS;
    out[0] = (float)(data + model);
  }
}

extern "C" void kernel_launch(void* const* d_in, const int* in_sizes, int n_in,
                              void* d_out, int out_size, void* d_ws, size_t ws_size,
                              hipStream_t stream)
{
  const float* x      = (const float*)d_in[0];
  const float* lam1   = (const float*)d_in[1];
  const float* lam2   = (const float*)d_in[2];
  const float* rp     = (const float*)d_in[3];
  const float* params = (const float*)d_in[4];

  char* ws = (char*)d_ws;
  double* pSums = (double*)ws;              // 16 B
  float*  bestL = (float*)(ws + 16);        // 2048 B -> ends 2064
  double* bitsF = (double*)(ws + 2064);     // 2048 B -> ends 4112

  int chunks = 512;
  while (chunks > 16) {
    size_t need = 4112 + (size_t)chunks * NFEAT * 18 * 4
                       + (size_t)chunks * NFEAT * 3 * 4;
    if (need <= ws_size) break;
    chunks >>= 1;
  }
  float* P1 = (float*)(ws + 4112);
  float* P2 = (float*)(ws + 4112 + (size_t)chunks * NFEAT * 18 * 4);
  int rowsPerBlock = NROWS / chunks;

  hipMemsetAsync(pSums, 0, 16, stream);
  k_pass1<<<chunks, 256, 0, stream>>>(x, lam1, lam2, rp, P1, rowsPerBlock);
  k_pick<<<NFEAT, 64, 0, stream>>>(P1, lam1, lam2, rp, bestL, chunks);
  k_pass2<<<chunks, 256, 0, stream>>>(x, bestL, P2, rowsPerBlock);
  k_featbits<<<NFEAT, 64, 0, stream>>>(P2, bitsF, chunks);
  k_param_reduce<<<512, 256, 0, stream>>>(params, pSums);
  k_final<<<1, 256, 0, stream>>>(bitsF, pSums, (float*)d_out);
}

// Round 3
// 100.858 us; speedup vs baseline: 2.3907x; 2.3907x over previous
//
#include <hip/hip_runtime.h>
#include <math.h>

#define NFEAT 256
#define NROWS 65536
#define PCOUNT 4194304
#define CH 512                       // pass1 grid / partial-set count
#define ROWS_PER_BLOCK (NROWS / CH)  // 128
#define F_EPS 5.9604645e-07f         // float32 eps * 5
#define F_LN2 0.69314718056f

#define FAST_LOG2(v) __builtin_log2f(v)   // v_log_f32
#define FAST_EXP2(v) __builtin_exp2f(v)   // v_exp_f32

constexpr double D_LN2 = 0.6931471805599453;
constexpr double D_HALF_LOG2_2PIE = 0.5 * 2.8378770664093453 / 0.6931471805599453;
constexpr double D_LAMBDA_BITS = 13.287712379549449; // 2*log2(100)

__device__ inline double wave_reduce_add(double v) {
  for (int o = 32; o > 0; o >>= 1) v += __shfl_down(v, o, 64);
  return v;
}

// flag: 1 if every proposal of every feature avoids the lambda special cases.
__global__ __launch_bounds__(256) void k_precheck(
    const float* __restrict__ lam1, const float* __restrict__ lam2,
    const float* __restrict__ rp, int* __restrict__ flag)
{
  __shared__ int bad;
  const int t = threadIdx.x;
  if (t == 0) bad = 0;
  __syncthreads();
  const float L1 = lam1[t], L2 = lam2[t];
  bool b = false;
#pragma unroll
  for (int j = 0; j < 6; ++j) {
    float l1 = (j == 0) ? L1 : L1 + 0.1f * rp[t * 10 + 2 * (j - 1)];
    float l2 = (j == 0) ? L2 : L2 + 0.1f * rp[t * 10 + 2 * (j - 1) + 1];
    b = b || (fabsf(l1) < F_EPS) || (fabsf(l2 - 2.0f) < F_EPS);
  }
  if (b) bad = 1;  // benign same-value race
  __syncthreads();
  if (t == 0) *flag = bad ? 0 : 1;
}

// Pass 1 body. Block c covers rows [c*128, c*128+128), split into `subs`
// row-subsets of 1024-thread blocks. t = feature = tid&255.
// Partials layout: P1[(k*NFEAT + f)*CH + c], k: 0..5 sum_y, 6..11 sum_y2,
// 12 sum_u2(pos), 13 sum_u2(neg). u2 = log2(1+|x|).
template <bool GENERAL>
__device__ inline void pass1_body(
    const float* __restrict__ x, const float* __restrict__ lam1,
    const float* __restrict__ lam2, const float* __restrict__ rp,
    float* __restrict__ P1)
{
  const int t = threadIdx.x & 255;
  const int sub = threadIdx.x >> 8;
  const int subs = blockDim.x >> 8;          // 4
  const int rowsPerThread = ROWS_PER_BLOCK / subs;
  const int c = blockIdx.x;

  const float L1 = lam1[t], L2 = lam2[t];
  float a_p[6], a_n[6], s_p[6], s_n[6];
  float t_p[6], t_n[6];
#pragma unroll
  for (int j = 0; j < 6; ++j) {
    float l1 = (j == 0) ? L1 : L1 + 0.1f * rp[t * 10 + 2 * (j - 1)];
    float l2 = (j == 0) ? L2 : L2 + 0.1f * rp[t * 10 + 2 * (j - 1) + 1];
    float tm = 2.0f - l2;
    if (GENERAL) {
      bool z1 = fabsf(l1) < F_EPS;
      bool z2 = fabsf(l2 - 2.0f) < F_EPS;
      a_p[j] = z1 ? 0.0f : l1;
      s_p[j] = z1 ? 0.0f : 1.0f / l1;
      t_p[j] = z1 ? F_LN2 : 0.0f;       // y = u = ln2*u2
      a_n[j] = z2 ? 0.0f : tm;
      s_n[j] = z2 ? 0.0f : -1.0f / tm;
      t_n[j] = z2 ? -F_LN2 : 0.0f;
    } else {
      a_p[j] = l1;       s_p[j] = 1.0f / l1;
      a_n[j] = tm;       s_n[j] = -1.0f / tm;
      t_p[j] = 0.0f;     t_n[j] = 0.0f;  // unused
    }
  }

  float as[6], aq[6];
#pragma unroll
  for (int j = 0; j < 6; ++j) { as[j] = 0.f; aq[j] = 0.f; }
  float u2p = 0.f, u2n = 0.f;

  const float* xp = x + ((size_t)c * ROWS_PER_BLOCK + sub * rowsPerThread) * NFEAT + t;
#pragma unroll 2
  for (int i = 0; i < rowsPerThread; ++i) {
    float v = xp[(size_t)i * NFEAT];
    bool pos = v >= 0.0f;
    float u2 = FAST_LOG2(1.0f + fabsf(v));
    float up = pos ? u2 : 0.0f;
    u2p += up;
    u2n += (u2 - up);
#pragma unroll
    for (int j = 0; j < 6; ++j) {
      float a = pos ? a_p[j] : a_n[j];
      float s = pos ? s_p[j] : s_n[j];
      float e = FAST_EXP2(a * u2);
      float w = e - 1.0f;
      float y = s * w;
      if (GENERAL) {
        float tt = pos ? t_p[j] : t_n[j];
        y = fmaf(tt, u2, y);
      }
      as[j] += y;
      aq[j] = fmaf(y, y, aq[j]);
    }
  }

  // in-block reduction across row-subsets
  __shared__ float red[14][NFEAT];
  float acc[14];
#pragma unroll
  for (int j = 0; j < 6; ++j) { acc[j] = as[j]; acc[6 + j] = aq[j]; }
  acc[12] = u2p; acc[13] = u2n;
  for (int s = 1; s < subs; ++s) {
    if (sub == s) {
#pragma unroll
      for (int k = 0; k < 14; ++k) red[k][t] = acc[k];
    }
    __syncthreads();
    if (sub == 0) {
#pragma unroll
      for (int k = 0; k < 14; ++k) acc[k] += red[k][t];
    }
    __syncthreads();
  }
  if (sub == 0) {
#pragma unroll
    for (int k = 0; k < 14; ++k)
      P1[((size_t)k * NFEAT + t) * CH + c] = acc[k];
  }
}

__global__ __launch_bounds__(1024, 8) void k_pass1_simple(
    const float* __restrict__ x, const float* __restrict__ lam1,
    const float* __restrict__ lam2, const float* __restrict__ rp,
    float* __restrict__ P1, const int* __restrict__ flag)
{
  if (*flag == 0) return;
  pass1_body<false>(x, lam1, lam2, rp, P1);
}

__global__ __launch_bounds__(1024) void k_pass1_general(
    const float* __restrict__ x, const float* __restrict__ lam1,
    const float* __restrict__ lam2, const float* __restrict__ rp,
    float* __restrict__ P1, const int* __restrict__ flag)
{
  if (*flag != 0) return;
  pass1_body<true>(x, lam1, lam2, rp, P1);
}

// Per feature: reduce partials (coalesced over c), compute 6 scores in f64,
// emit bits = min score; tie -> flag for the fallback pass2.
__global__ __launch_bounds__(64) void k_pick(
    const float* __restrict__ P1, const float* __restrict__ lam1,
    const float* __restrict__ lam2, const float* __restrict__ rp,
    float* __restrict__ bestL, int* __restrict__ tied,
    double* __restrict__ bitsF)
{
  const int f = blockIdx.x;
  const int lane = threadIdx.x;
  double s[14];
#pragma unroll
  for (int k = 0; k < 14; ++k) s[k] = 0.0;
  for (int c = lane; c < CH; c += 64) {
#pragma unroll
    for (int k = 0; k < 14; ++k)
      s[k] += (double)P1[((size_t)k * NFEAT + f) * CH + c];
  }
#pragma unroll
  for (int k = 0; k < 14; ++k) s[k] = wave_reduce_add(s[k]);

  if (lane == 0) {
    const float L1 = lam1[f], L2 = lam2[f];
    const double n = (double)NROWS;
    double scores[6], al1[6], al2[6];
#pragma unroll
    for (int j = 0; j < 6; ++j) {
      float l1 = (j == 0) ? L1 : L1 + 0.1f * rp[f * 10 + 2 * (j - 1)];
      float l2 = (j == 0) ? L2 : L2 + 0.1f * rp[f * 10 + 2 * (j - 1) + 1];
      al1[j] = (double)l1; al2[j] = (double)l2;
      bool z1 = fabsf(l1) < F_EPS;
      bool z2 = fabsf(l2 - 2.0f) < F_EPS;
      double ccp = z1 ? -1.0 : (double)l1 - 1.0;
      double ccn = z2 ? -1.0 : 1.0 - (double)l2;
      // lj_bits: u = ln2*u2, /ln2 for bits -> coefficients apply to u2 sums
      double ljb = ccp * s[12] + ccn * s[13];
      double mean = s[j] / n;
      double var = s[6 + j] / n - mean * mean;
      var = var > 1e-12 ? var : 1e-12;
      scores[j] = n * (D_HALF_LOG2_2PIE + 0.5 * log2(var)) + ljb + D_LAMBDA_BITS;
    }
    double mn = scores[0];
#pragma unroll
    for (int j = 1; j < 6; ++j) mn = scores[j] < mn ? scores[j] : mn;
    double wsum = 0.0, b1 = 0.0, b2 = 0.0;
#pragma unroll
    for (int j = 0; j < 6; ++j) {
      double w = (scores[j] == mn) ? 1.0 : 0.0;
      wsum += w; b1 += w * al1[j]; b2 += w * al2[j];
    }
    bestL[2 * f]     = (float)(b1 / wsum);
    bestL[2 * f + 1] = (float)(b2 / wsum);
    tied[f] = (wsum > 1.5) ? 1 : 0;
    bitsF[f] = mn;   // unique min: identical to re-evaluating at best lambda
  }
}

// Fallback pass 2: only does work if some feature tied (averaged lambda is new).
// Writes P2[(k*NFEAT+t)*CH + c], k=0 sum_y, k=1 sum_y2.
__global__ __launch_bounds__(256) void k_pass2(
    const float* __restrict__ x, const float* __restrict__ bestL,
    const int* __restrict__ tied, float* __restrict__ P2)
{
  __shared__ int any;
  const int t = threadIdx.x;
  if (t == 0) any = 0;
  __syncthreads();
  if (tied[t]) any = 1;
  __syncthreads();
  if (!any) return;

  const int c = blockIdx.x;
  const float l1 = bestL[2 * t], l2 = bestL[2 * t + 1];
  const bool z1 = fabsf(l1) < F_EPS;
  const bool z2 = fabsf(l2 - 2.0f) < F_EPS;
  const float tm = 2.0f - l2;
  const float a_p = z1 ? 0.f : l1,  s_pv = z1 ? 0.f : 1.f / l1,  t_pv = z1 ? F_LN2 : 0.f;
  const float a_n = z2 ? 0.f : tm,  s_nv = z2 ? 0.f : -1.f / tm, t_nv = z2 ? -F_LN2 : 0.f;

  float sy = 0.f, sq = 0.f;
  const float* xp = x + (size_t)c * ROWS_PER_BLOCK * NFEAT + t;
  for (int i = 0; i < ROWS_PER_BLOCK; ++i) {
    float v = xp[(size_t)i * NFEAT];
    bool pos = v >= 0.0f;
    float u2 = FAST_LOG2(1.0f + fabsf(v));
    float a = pos ? a_p : a_n;
    float s = pos ? s_pv : s_nv;
    float tt = pos ? t_pv : t_nv;
    float e = FAST_EXP2(a * u2);
    float y = fmaf(tt, u2, s * (e - 1.0f));
    sy += y;
    sq = fmaf(y, y, sq);
  }
  P2[((size_t)0 * NFEAT + t) * CH + c] = sy;
  P2[((size_t)1 * NFEAT + t) * CH + c] = sq;
}

__global__ __launch_bounds__(64) void k_featbits(
    const float* __restrict__ P1, const float* __restrict__ P2,
    const float* __restrict__ bestL, const int* __restrict__ tied,
    double* __restrict__ bitsF)
{
  const int f = blockIdx.x;
  if (!tied[f]) return;
  const int lane = threadIdx.x;
  double s0 = 0.0, s1 = 0.0, sup = 0.0, sun = 0.0;
  for (int c = lane; c < CH; c += 64) {
    s0  += (double)P2[((size_t)0 * NFEAT + f) * CH + c];
    s1  += (double)P2[((size_t)1 * NFEAT + f) * CH + c];
    sup += (double)P1[((size_t)12 * NFEAT + f) * CH + c];
    sun += (double)P1[((size_t)13 * NFEAT + f) * CH + c];
  }
  s0 = wave_reduce_add(s0); s1 = wave_reduce_add(s1);
  sup = wave_reduce_add(sup); sun = wave_reduce_add(sun);
  if (lane == 0) {
    const float l1 = bestL[2 * f], l2 = bestL[2 * f + 1];
    bool z1 = fabsf(l1) < F_EPS;
    bool z2 = fabsf(l2 - 2.0f) < F_EPS;
    double ccp = z1 ? -1.0 : (double)l1 - 1.0;
    double ccn = z2 ? -1.0 : 1.0 - (double)l2;
    double ljb = ccp * sup + ccn * sun;
    const double n = (double)NROWS;
    double mean = s0 / n;
    double var = s1 / n - mean * mean;
    var = var > 1e-12 ? var : 1e-12;
    bitsF[f] = n * (D_HALF_LOG2_2PIE + 0.5 * log2(var)) + ljb + D_LAMBDA_BITS;
  }
}

__global__ __launch_bounds__(256) void k_param_reduce(
    const float* __restrict__ p, double* __restrict__ pSums)
{
  const float4* p4 = (const float4*)p;
  const size_t n4 = PCOUNT / 4;
  double s = 0.0, q = 0.0;
  for (size_t i = (size_t)blockIdx.x * 256 + threadIdx.x; i < n4;
       i += (size_t)gridDim.x * 256) {
    float4 v = p4[i];
    s += (double)v.x + (double)v.y + (double)v.z + (double)v.w;
    q += (double)v.x * v.x + (double)v.y * v.y
       + (double)v.z * v.z + (double)v.w * v.w;
  }
  s = wave_reduce_add(s); q = wave_reduce_add(q);
  __shared__ double ls[4], lq[4];
  int w = threadIdx.x >> 6;
  if ((threadIdx.x & 63) == 0) { ls[w] = s; lq[w] = q; }
  __syncthreads();
  if (threadIdx.x == 0) {
    atomicAdd(&pSums[0], ls[0] + ls[1] + ls[2] + ls[3]);
    atomicAdd(&pSums[1], lq[0] + lq[1] + lq[2] + lq[3]);
  }
}

__global__ __launch_bounds__(256) void k_final(
    const double* __restrict__ bitsF, const double* __restrict__ pSums,
    float* __restrict__ out)
{
  __shared__ double l[4];
  double s = bitsF[threadIdx.x];
  s = wave_reduce_add(s);
  int w = threadIdx.x >> 6;
  if ((threadIdx.x & 63) == 0) l[w] = s;
  __syncthreads();
  if (threadIdx.x == 0) {
    double data = l[0] + l[1] + l[2] + l[3];
    const double n = (double)PCOUNT;
    double mean = pSums[0] / n;
    double var = pSums[1] / n - mean * mean;
    var = var > 1e-12 ? var : 1e-12;
    double model = n * (D_HALF_LOG2_2PIE + 0.5 * log2(var)) + D_LAMBDA_BITS;
    out[0] = (float)(data + model);
  }
}

extern "C" void kernel_launch(void* const* d_in, const int* in_sizes, int n_in,
                              void* d_out, int out_size, void* d_ws, size_t ws_size,
                              hipStream_t stream)
{
  const float* x      = (const float*)d_in[0];
  const float* lam1   = (const float*)d_in[1];
  const float* lam2   = (const float*)d_in[2];
  const float* rp     = (const float*)d_in[3];
  const float* params = (const float*)d_in[4];

  char* ws = (char*)d_ws;
  double* pSums = (double*)ws;                 // 16 B
  float*  bestL = (float*)(ws + 16);           // 2048 B -> 2064
  double* bitsF = (double*)(ws + 2064);        // 2048 B -> 4112
  int*    tied  = (int*)(ws + 4112);           // 1024 B -> 5136
  int*    flag  = (int*)(ws + 5136);           // 4 B
  float*  P1    = (float*)(ws + 5376);         // 14*256*512*4 = 7,340,032
  float*  P2    = (float*)(ws + 5376 + (size_t)14 * NFEAT * CH * 4); // 1 MiB

  (void)hipMemsetAsync(pSums, 0, 16, stream);
  k_precheck<<<1, 256, 0, stream>>>(lam1, lam2, rp, flag);
  k_pass1_simple<<<CH, 1024, 0, stream>>>(x, lam1, lam2, rp, P1, flag);
  k_pass1_general<<<CH, 1024, 0, stream>>>(x, lam1, lam2, rp, P1, flag);
  k_pick<<<NFEAT, 64, 0, stream>>>(P1, lam1, lam2, rp, bestL, tied, bitsF);
  k_pass2<<<CH, 256, 0, stream>>>(x, bestL, tied, P2);
  k_featbits<<<NFEAT, 64, 0, stream>>>(P1, P2, bestL, tied, bitsF);
  k_param_reduce<<<512, 256, 0, stream>>>(params, pSums);
  k_final<<<1, 256, 0, stream>>>(bitsF, pSums, (float*)d_out);
}